// Round 2
// baseline (669.807 us; speedup 1.0000x reference)
//
#include <hip/hip_runtime.h>
#include <hip/hip_bf16.h>
#include <stdint.h>

#define B_ 2
#define N_ 2048
#define M_ 2048
#define C_ 1024
#define H_ 16
#define D_ 64

typedef __attribute__((ext_vector_type(8))) short s16x8;
typedef __attribute__((ext_vector_type(4))) short s16x4;
typedef __attribute__((ext_vector_type(4))) float f32x4;
typedef __attribute__((ext_vector_type(16))) float f32x16;

__device__ __attribute__((always_inline)) inline short f2b(float f){
    __hip_bfloat16 h = __float2bfloat16(f); short s; __builtin_memcpy(&s, &h, 2); return s;
}

#define MFMA16(a,b,c) __builtin_amdgcn_mfma_f32_16x16x32_bf16(a,b,c,0,0,0)
#define MFMA32(a,b,c) __builtin_amdgcn_mfma_f32_32x32x16_bf16(a,b,c,0,0,0)

__device__ __attribute__((always_inline)) inline void gl_lds16(const void* g, void* l){
    __builtin_amdgcn_global_load_lds((__attribute__((address_space(1))) void*)g,
                                     (__attribute__((address_space(3))) void*)l, 16, 0, 0);
}
__device__ __attribute__((always_inline)) inline unsigned fbits(float f){
    unsigned u; __builtin_memcpy(&u, &f, 4); return u;
}

// ---------------- fused f32 -> bf16 convert: [query|key|Wq|Wk|Wv|Wo] -> ws[0..12M) ----
__global__ void cvt_all(const float* __restrict__ q, const float* __restrict__ k,
                        const float* __restrict__ wq, const float* __restrict__ wk,
                        const float* __restrict__ wv, const float* __restrict__ wo,
                        short* __restrict__ dst){
    long i = ((long)blockIdx.x * 256 + threadIdx.x) * 8;
    const float* src; long off;
    if      (i <  4194304L){ src = q;  off = i; }
    else if (i <  8388608L){ src = k;  off = i - 4194304L; }
    else if (i <  9437184L){ src = wq; off = i - 8388608L; }
    else if (i < 10485760L){ src = wk; off = i - 9437184L; }
    else if (i < 11534336L){ src = wv; off = i - 10485760L; }
    else                   { src = wo; off = i - 11534336L; }
    float4 a = *(const float4*)(src + off);
    float4 b = *(const float4*)(src + off + 4);
    s16x8 o;
    o[0]=f2b(a.x); o[1]=f2b(a.y); o[2]=f2b(a.z); o[3]=f2b(a.w);
    o[4]=f2b(b.x); o[5]=f2b(b.y); o[6]=f2b(b.z); o[7]=f2b(b.w);
    *(s16x8*)(dst + i) = o;
}

// ---------------- fused QKV projection GEMM ----------------
// A = qbf (n<1024) or kbf; W = [Wq;Wk;Wv] (3072,1024). Epilogue: q/k -> RoPE (+bq,
// q also scaled by D^-0.5*log2e), v -> +bv and stored transposed as vT[b,h,d,m].
__global__ __launch_bounds__(256, 3) void gemm_proj(
    const short* __restrict__ qbf, const short* __restrict__ kbf,
    const short* __restrict__ W,
    const float* __restrict__ bq, const float* __restrict__ bv,
    const int* __restrict__ qpos, const int* __restrict__ kpos,
    short* __restrict__ qproj, short* __restrict__ kproj, short* __restrict__ vT)
{
    __shared__ short As[128 * 32];
    __shared__ short Bs[128 * 32];
    const int n0 = blockIdx.x * 128, m0 = blockIdx.y * 128;
    const int sel = n0 >> 10;                 // 0=q, 1=k, 2=v
    const short* A = (sel == 0) ? qbf : kbf;
    const int tid = threadIdx.x, lane = tid & 63, wave = tid >> 6;
    const int quad = lane >> 4, l16 = lane & 15;
    const int wr = (wave >> 1) * 64, wc = (wave & 1) * 64;
    const int srow = lane >> 2, scol = (lane & 3) * 8;

    f32x4 acc[4][4] = {};

    const short* Ag = A + (size_t)(m0 + wave * 32 + srow) * C_ + scol;
    const short* Bg = W + (size_t)(n0 + wave * 32 + srow) * C_ + scol;
    short* lA0 = As + (wave * 32) * 32;
    short* lA1 = As + (wave * 32 + 16) * 32;
    short* lB0 = Bs + (wave * 32) * 32;
    short* lB1 = Bs + (wave * 32 + 16) * 32;

    for (int k0 = 0; k0 < C_; k0 += 32){
        __syncthreads();
        gl_lds16(Ag + k0, lA0);
        gl_lds16(Ag + k0 + 16 * (size_t)C_, lA1);
        gl_lds16(Bg + k0, lB0);
        gl_lds16(Bg + k0 + 16 * (size_t)C_, lB1);
        __syncthreads();
        s16x8 af[4], bfr[4];
        #pragma unroll
        for (int t = 0; t < 4; t++) af[t]  = *(const s16x8*)&As[(wr + t*16 + l16) * 32 + quad * 8];
        #pragma unroll
        for (int t = 0; t < 4; t++) bfr[t] = *(const s16x8*)&Bs[(wc + t*16 + l16) * 32 + quad * 8];
        #pragma unroll
        for (int i = 0; i < 4; i++)
            #pragma unroll
            for (int j = 0; j < 4; j++)
                acc[i][j] = MFMA16(af[i], bfr[j], acc[i][j]);
    }

    // C/D layout: row(m) = quad*4 + r, col(n) = l16 (+16*j +64*wc-tile)
    if (sel <= 1){
        const int* pos_arr = sel ? kpos : qpos;
        short* dst = sel ? kproj : qproj;
        const int cbase = n0 - sel * 1024;
        const float fac = sel ? 1.0f : 0.18033688011112042f;  // 0.125*log2(e)
        #pragma unroll
        for (int j = 0; j < 2; j++){
            int i_rot = j * 16 + l16;                           // 0..31
            float invf = exp2f(-(float)i_rot * (13.287712379549449f / 32.0f));
            int c1 = cbase + wc + j * 16 + l16;
            float b1 = sel ? 0.f : bq[c1];
            float b2 = sel ? 0.f : bq[c1 + 32];
            #pragma unroll
            for (int i = 0; i < 4; i++){
                int row = m0 + wr + i * 16 + quad * 4;
                #pragma unroll
                for (int r = 0; r < 4; r++){
                    int rw = row + r;
                    float ang = (float)pos_arr[rw] * invf;
                    float cs = cosf(ang), sn = sinf(ang);
                    float x1 = acc[i][j][r] + b1;
                    float x2 = acc[i][j + 2][r] + b2;
                    dst[(size_t)rw * C_ + c1]      = f2b((x1 * cs - x2 * sn) * fac);
                    dst[(size_t)rw * C_ + c1 + 32] = f2b((x2 * cs + x1 * sn) * fac);
                }
            }
        }
    } else {
        #pragma unroll
        for (int j = 0; j < 4; j++){
            int col = n0 - 2048 + wc + j * 16 + l16;            // 0..1023
            int h = col >> 6, d = col & 63;
            float bb = bv[col];
            #pragma unroll
            for (int i = 0; i < 4; i++){
                int row = m0 + wr + i * 16 + quad * 4;
                int b = row >> 11, m = row & 2047;
                unsigned u0 = (unsigned)(unsigned short)f2b(acc[i][j][0] + bb) |
                              ((unsigned)(unsigned short)f2b(acc[i][j][1] + bb) << 16);
                unsigned u1 = (unsigned)(unsigned short)f2b(acc[i][j][2] + bb) |
                              ((unsigned)(unsigned short)f2b(acc[i][j][3] + bb) << 16);
                uint2 u; u.x = u0; u.y = u1;
                *(uint2*)&vT[(((size_t)(b * H_ + h)) * D_ + d) * M_ + m] = u;
            }
        }
    }
}

// ---------------- final projection + bias + residual (f32 out) ----------------
__global__ __launch_bounds__(256, 2) void gemm_out(
    const short* __restrict__ A, const short* __restrict__ W,
    const float* __restrict__ bias, const float* __restrict__ resid,
    float* __restrict__ outf)
{
    __shared__ short As[128 * 32];
    __shared__ short Bs[128 * 32];
    const int n0 = blockIdx.x * 128, m0 = blockIdx.y * 128;
    const int tid = threadIdx.x, lane = tid & 63, wave = tid >> 6;
    const int quad = lane >> 4, l16 = lane & 15;
    const int wr = (wave >> 1) * 64, wc = (wave & 1) * 64;
    const int srow = lane >> 2, scol = (lane & 3) * 8;

    f32x4 acc[4][4] = {};
    const short* Ag = A + (size_t)(m0 + wave * 32 + srow) * C_ + scol;
    const short* Bg = W + (size_t)(n0 + wave * 32 + srow) * C_ + scol;
    short* lA0 = As + (wave * 32) * 32;
    short* lA1 = As + (wave * 32 + 16) * 32;
    short* lB0 = Bs + (wave * 32) * 32;
    short* lB1 = Bs + (wave * 32 + 16) * 32;

    for (int k0 = 0; k0 < C_; k0 += 32){
        __syncthreads();
        gl_lds16(Ag + k0, lA0);
        gl_lds16(Ag + k0 + 16 * (size_t)C_, lA1);
        gl_lds16(Bg + k0, lB0);
        gl_lds16(Bg + k0 + 16 * (size_t)C_, lB1);
        __syncthreads();
        s16x8 af[4], bfr[4];
        #pragma unroll
        for (int t = 0; t < 4; t++) af[t]  = *(const s16x8*)&As[(wr + t*16 + l16) * 32 + quad * 8];
        #pragma unroll
        for (int t = 0; t < 4; t++) bfr[t] = *(const s16x8*)&Bs[(wc + t*16 + l16) * 32 + quad * 8];
        #pragma unroll
        for (int i = 0; i < 4; i++)
            #pragma unroll
            for (int j = 0; j < 4; j++)
                acc[i][j] = MFMA16(af[i], bfr[j], acc[i][j]);
    }

    #pragma unroll
    for (int j = 0; j < 4; j++){
        int c = n0 + wc + j * 16 + l16;
        float bb = bias[c];
        #pragma unroll
        for (int i = 0; i < 4; i++){
            int row = m0 + wr + i * 16 + quad * 4;
            #pragma unroll
            for (int r = 0; r < 4; r++){
                size_t idx = (size_t)(row + r) * C_ + c;
                outf[idx] = acc[i][j][r] + bb + resid[idx];
            }
        }
    }
}

// ---------------- Flash attention (32x32x16 MFMA, S^T trick) ----------------
// Block: 128 queries, one (b,h). 4 waves as (wq, kq) 2x2 over a 128q x 64k stage.
// Per wave-stage: S^T = K.Q^T (C-layout rows=key -> b64-packed P writes into
// [q][key] LDS), PV reads P as A-frags (b64 pairs). LDS ping-pong, 1 barrier/stage.
__global__ __launch_bounds__(256, 2) void flash_attn(
    const short* __restrict__ q, const short* __restrict__ k,
    const short* __restrict__ vt, short* __restrict__ o)
{
    // shorts: K[2] @0 (2*64*68), V[2] @8704, Ps @17408 (4 * 64*36), Lsum/Linv @26624
    __shared__ short smem[27136];
    const int b = blockIdx.y >> 4, h = blockIdx.y & 15;
    const int n0 = blockIdx.x * 128;
    const int tid = threadIdx.x, lane = tid & 63, wave = tid >> 6;
    const int hi = lane >> 5, l32 = lane & 31;
    const int wq = wave & 1, kq = wave >> 1;

    // Q fragments in registers (B-operand: B[k=d][n=query])
    s16x8 qf[2][4];
    #pragma unroll
    for (int qt = 0; qt < 2; qt++)
        #pragma unroll
        for (int c = 0; c < 4; c++)
            qf[qt][c] = *(const s16x8*)&q[((size_t)(b * N_ + n0 + wq * 64 + qt * 32 + l32)) * C_
                                          + h * D_ + c * 16 + hi * 8];

    const short* kg = k  + (size_t)(b * M_) * C_ + h * D_;
    const short* vg = vt + ((size_t)(b * H_ + h)) * D_ * M_;
    const int srow0 = tid >> 3, sseg = (tid & 7) * 8;

    union V8 { s16x8 v; uint2 u[2]; };
    V8 kreg[2], vreg[2];

    // prologue: stage 0
    #pragma unroll
    for (int ii = 0; ii < 2; ii++){
        int row = srow0 + 32 * ii;
        kreg[ii].v = *(const s16x8*)&kg[(size_t)row * C_ + sseg];
        vreg[ii].v = *(const s16x8*)&vg[(size_t)row * M_ + sseg];
    }
    #pragma unroll
    for (int ii = 0; ii < 2; ii++){
        int row = srow0 + 32 * ii;
        short* kd = &smem[row * 68 + sseg];
        *(uint2*)kd = kreg[ii].u[0]; *(uint2*)(kd + 4) = kreg[ii].u[1];
        short* vd = &smem[8704 + row * 68 + sseg];
        *(uint2*)vd = vreg[ii].u[0]; *(uint2*)(vd + 4) = vreg[ii].u[1];
    }

    f32x16 zero16 = {};
    f32x16 oacc[2][2] = {zero16, zero16, zero16, zero16};
    float lacc[2] = {0.f, 0.f};
    short* Pw = &smem[17408 + wave * 2304];

    for (int st = 0; st < 32; st++){
        const int p = st & 1;
        __syncthreads();
        if (st < 31){
            #pragma unroll
            for (int ii = 0; ii < 2; ii++){
                int row = srow0 + 32 * ii;
                kreg[ii].v = *(const s16x8*)&kg[((size_t)((st + 1) * 64 + row)) * C_ + sseg];
                vreg[ii].v = *(const s16x8*)&vg[(size_t)row * M_ + (st + 1) * 64 + sseg];
            }
        }
        const short* Kp = &smem[p * 4352];
        const short* Vp = &smem[8704 + p * 4352];

        // A-frags of K for this wave's 32-key strip
        s16x4 kf[4][2];
        #pragma unroll
        for (int c = 0; c < 4; c++){
            const short* a = &Kp[(kq * 32 + l32) * 68 + c * 16 + hi * 8];
            kf[c][0] = *(const s16x4*)a; kf[c][1] = *(const s16x4*)(a + 4);
        }
        #pragma unroll
        for (int qt = 0; qt < 2; qt++){
            f32x16 sv = {};
            #pragma unroll
            for (int c = 0; c < 4; c++){
                s16x8 ka = __builtin_shufflevector(kf[c][0], kf[c][1], 0,1,2,3,4,5,6,7);
                sv = MFMA32(ka, qf[qt][c], sv);
            }
            float ls = 0.f;
            unsigned pb[8];
            #pragma unroll
            for (int g = 0; g < 4; g++){
                float p0 = __builtin_amdgcn_exp2f(sv[4*g+0]);
                float p1 = __builtin_amdgcn_exp2f(sv[4*g+1]);
                float p2 = __builtin_amdgcn_exp2f(sv[4*g+2]);
                float p3 = __builtin_amdgcn_exp2f(sv[4*g+3]);
                ls += (p0 + p1) + (p2 + p3);
                pb[2*g]   = __builtin_amdgcn_perm(fbits(p1), fbits(p0), 0x07060302);
                pb[2*g+1] = __builtin_amdgcn_perm(fbits(p3), fbits(p2), 0x07060302);
            }
            lacc[qt] += ls;
            #pragma unroll
            for (int g = 0; g < 4; g++){
                short* d = &Pw[(qt * 32 + l32) * 36 + 8 * g + 4 * hi];
                uint2 u; u.x = pb[2*g]; u.y = pb[2*g+1];
                *(uint2*)d = u;
            }
        }
        asm volatile("s_waitcnt lgkmcnt(0)" ::: "memory");

        // PV: O[q][d] += P(64x32) . V(32x64)
        s16x8 pf[2][2], vf[2][2];
        #pragma unroll
        for (int qt = 0; qt < 2; qt++)
            #pragma unroll
            for (int c = 0; c < 2; c++){
                const short* a = &Pw[(qt * 32 + l32) * 36 + c * 16 + hi * 8];
                pf[qt][c] = __builtin_shufflevector(*(const s16x4*)a, *(const s16x4*)(a + 4),
                                                    0,1,2,3,4,5,6,7);
            }
        #pragma unroll
        for (int dt = 0; dt < 2; dt++)
            #pragma unroll
            for (int c = 0; c < 2; c++){
                const short* a = &Vp[(dt * 32 + l32) * 68 + kq * 32 + c * 16 + hi * 8];
                vf[dt][c] = __builtin_shufflevector(*(const s16x4*)a, *(const s16x4*)(a + 4),
                                                    0,1,2,3,4,5,6,7);
            }
        #pragma unroll
        for (int qt = 0; qt < 2; qt++)
            #pragma unroll
            for (int dt = 0; dt < 2; dt++)
                #pragma unroll
                for (int c = 0; c < 2; c++)
                    oacc[qt][dt] = MFMA32(pf[qt][c], vf[dt][c], oacc[qt][dt]);

        __syncthreads();
        if (st < 31){
            int pn = p ^ 1;
            #pragma unroll
            for (int ii = 0; ii < 2; ii++){
                int row = srow0 + 32 * ii;
                short* kd = &smem[pn * 4352 + row * 68 + sseg];
                *(uint2*)kd = kreg[ii].u[0]; *(uint2*)(kd + 4) = kreg[ii].u[1];
                short* vd = &smem[8704 + pn * 4352 + row * 68 + sseg];
                *(uint2*)vd = vreg[ii].u[0]; *(uint2*)(vd + 4) = vreg[ii].u[1];
            }
        }
    }

    __syncthreads();   // everyone done with K/V/P buffers

    float* LO   = (float*)smem;            // [128][65] f32 (overlays K/V bufs)
    float* Lsum = (float*)&smem[26624];    // 128 f32
    float* Linv = Lsum + 128;              // 128 f32

    float l0[2];
    #pragma unroll
    for (int qt = 0; qt < 2; qt++)
        l0[qt] = lacc[qt] + __shfl_xor(lacc[qt], 32);

    if (kq == 1){
        #pragma unroll
        for (int qt = 0; qt < 2; qt++)
            Lsum[wq * 64 + qt * 32 + l32] = l0[qt];
        #pragma unroll
        for (int qt = 0; qt < 2; qt++)
            #pragma unroll
            for (int dt = 0; dt < 2; dt++)
                #pragma unroll
                for (int e = 0; e < 16; e++){
                    int qrow = wq * 64 + qt * 32 + (e & 3) + 8 * (e >> 2) + 4 * hi;
                    LO[qrow * 65 + dt * 32 + l32] = oacc[qt][dt][e];
                }
    }
    __syncthreads();
    if (kq == 0){
        #pragma unroll
        for (int qt = 0; qt < 2; qt++){
            float lt = l0[qt] + Lsum[wq * 64 + qt * 32 + l32];
            Linv[wq * 64 + qt * 32 + l32] = 1.0f / lt;
        }
        asm volatile("s_waitcnt lgkmcnt(0)" ::: "memory");
        #pragma unroll
        for (int qt = 0; qt < 2; qt++)
            #pragma unroll
            for (int dt = 0; dt < 2; dt++)
                #pragma unroll
                for (int e = 0; e < 16; e++){
                    int qrow = wq * 64 + qt * 32 + (e & 3) + 8 * (e >> 2) + 4 * hi;
                    float val = (oacc[qt][dt][e] + LO[qrow * 65 + dt * 32 + l32]) * Linv[qrow];
                    o[((size_t)(b * N_ + n0 + qrow)) * C_ + h * D_ + dt * 32 + l32] = f2b(val);
                }
    }
}

extern "C" void kernel_launch(void* const* d_in, const int* in_sizes, int n_in,
                              void* d_out, int out_size, void* d_ws, size_t ws_size,
                              hipStream_t stream) {
    const float* query = (const float*)d_in[0];
    const float* key   = (const float*)d_in[1];
    const int*   qpos  = (const int*)d_in[2];
    const int*   kpos  = (const int*)d_in[3];
    const float* Wq    = (const float*)d_in[4];
    const float* bq    = (const float*)d_in[5];
    const float* Wk    = (const float*)d_in[6];
    const float* Wv    = (const float*)d_in[7];
    const float* bv    = (const float*)d_in[8];
    const float* Wo    = (const float*)d_in[9];
    const float* bo    = (const float*)d_in[10];
    float* out = (float*)d_out;

    const size_t E4M = (size_t)4 * 1024 * 1024;
    const size_t E1M = (size_t)1024 * 1024;
    short* ws    = (short*)d_ws;
    short* qbf   = ws;                    // 4M (dead after proj -> reused as attn)
    short* kbf   = qbf   + E4M;           // 4M
    short* wqkvb = kbf   + E4M;           // 3M = [Wq;Wk;Wv]
    short* wob   = wqkvb + 3 * E1M;       // 1M
    short* qproj = wob   + E1M;           // 4M
    short* kproj = qproj + E4M;           // 4M
    short* vT    = kproj + E4M;           // 4M  -> total 24M shorts = 48 MB
    short* attn  = qbf;                   // alias

    // 1) fused converts (12M elements, contiguous dst)
    cvt_all<<<6144, 256, 0, stream>>>(query, key, Wq, Wk, Wv, Wo, ws);

    // 2) fused QKV projection + RoPE + V-transpose epilogues
    gemm_proj<<<dim3(24, 32), 256, 0, stream>>>(qbf, kbf, wqkvb, bq, bv,
                                                qpos, kpos, qproj, kproj, vT);

    // 3) flash attention -> attn [B,N,C] bf16
    flash_attn<<<dim3(16, 32), 256, 0, stream>>>(qproj, kproj, vT, attn);

    // 4) output projection + bias + residual -> f32 out
    gemm_out<<<dim3(8, 32), 256, 0, stream>>>(attn, wob, bo, query, out);
}

// Round 3
// 235.472 us; speedup vs baseline: 2.8445x; 2.8445x over previous
//
#include <hip/hip_runtime.h>
#include <hip/hip_bf16.h>
#include <stdint.h>

#define B_ 2
#define N_ 2048
#define M_ 2048
#define C_ 1024
#define H_ 16
#define D_ 64

typedef __attribute__((ext_vector_type(8))) short s16x8;
typedef __attribute__((ext_vector_type(4))) short s16x4;
typedef __attribute__((ext_vector_type(4))) float f32x4;
typedef __attribute__((ext_vector_type(16))) float f32x16;

__device__ __attribute__((always_inline)) inline short f2b(float f){
    __hip_bfloat16 h = __float2bfloat16(f); short s; __builtin_memcpy(&s, &h, 2); return s;
}
__device__ __attribute__((always_inline)) inline float b2f(short s){
    __hip_bfloat16 h; __builtin_memcpy(&h, &s, 2); return __bfloat162float(h);
}

#define MFMA16(a,b,c) __builtin_amdgcn_mfma_f32_16x16x32_bf16(a,b,c,0,0,0)
#define MFMA32(a,b,c) __builtin_amdgcn_mfma_f32_32x32x16_bf16(a,b,c,0,0,0)

__device__ __attribute__((always_inline)) inline void gl_lds16(const void* g, void* l){
    __builtin_amdgcn_global_load_lds((__attribute__((address_space(1))) void*)g,
                                     (__attribute__((address_space(3))) void*)l, 16, 0, 0);
}
__device__ __attribute__((always_inline)) inline unsigned fbits(float f){
    unsigned u; __builtin_memcpy(&u, &f, 4); return u;
}

// ---------------- fused f32 -> bf16 convert: [query|key|Wq|Wk|Wv|Wo] -> ws[0..12M) ----
__global__ void cvt_all(const float* __restrict__ q, const float* __restrict__ k,
                        const float* __restrict__ wq, const float* __restrict__ wk,
                        const float* __restrict__ wv, const float* __restrict__ wo,
                        short* __restrict__ dst){
    long i = ((long)blockIdx.x * 256 + threadIdx.x) * 8;
    const float* src; long off;
    if      (i <  4194304L){ src = q;  off = i; }
    else if (i <  8388608L){ src = k;  off = i - 4194304L; }
    else if (i <  9437184L){ src = wq; off = i - 8388608L; }
    else if (i < 10485760L){ src = wk; off = i - 9437184L; }
    else if (i < 11534336L){ src = wv; off = i - 10485760L; }
    else                   { src = wo; off = i - 11534336L; }
    float4 a = *(const float4*)(src + off);
    float4 b = *(const float4*)(src + off + 4);
    s16x8 o;
    o[0]=f2b(a.x); o[1]=f2b(a.y); o[2]=f2b(a.z); o[3]=f2b(a.w);
    o[4]=f2b(b.x); o[5]=f2b(b.y); o[6]=f2b(b.z); o[7]=f2b(b.w);
    *(s16x8*)(dst + i) = o;
}

// ---------------- fused QKV projection GEMM (plain epilogue, round-1 proven) --------
// A = qbf (n0<1024) or kbf; W = [Wq;Wk;Wv] (3072,1024) bf16 row-major.
// Epilogue: three-way column split -> qproj(+bq) / kproj / vproj(+bv), scalar stores.
__global__ __launch_bounds__(256, 2) void gemm_qkv(
    const short* __restrict__ qbf, const short* __restrict__ kbf,
    const short* __restrict__ W,
    const float* __restrict__ bq, const float* __restrict__ bv,
    short* __restrict__ qproj, short* __restrict__ kproj, short* __restrict__ vproj)
{
    __shared__ short As[128 * 32];
    __shared__ short Bs[128 * 32];
    const int n0 = blockIdx.x * 128, m0 = blockIdx.y * 128;
    const int sel = n0 >> 10;                 // 0=q, 1=k, 2=v (block-uniform)
    const short* A = (sel == 0) ? qbf : kbf;
    const int tid = threadIdx.x, lane = tid & 63, wave = tid >> 6;
    const int quad = lane >> 4, l16 = lane & 15;
    const int wr = (wave >> 1) * 64, wc = (wave & 1) * 64;
    const int srow = lane >> 2, scol = (lane & 3) * 8;

    f32x4 acc[4][4] = {};

    const short* Ag = A + (size_t)(m0 + wave * 32 + srow) * C_ + scol;
    const short* Bg = W + (size_t)(n0 + wave * 32 + srow) * C_ + scol;
    short* lA0 = As + (wave * 32) * 32;
    short* lA1 = As + (wave * 32 + 16) * 32;
    short* lB0 = Bs + (wave * 32) * 32;
    short* lB1 = Bs + (wave * 32 + 16) * 32;

    for (int k0 = 0; k0 < C_; k0 += 32){
        __syncthreads();
        gl_lds16(Ag + k0, lA0);
        gl_lds16(Ag + k0 + 16 * (size_t)C_, lA1);
        gl_lds16(Bg + k0, lB0);
        gl_lds16(Bg + k0 + 16 * (size_t)C_, lB1);
        __syncthreads();
        s16x8 af[4], bfr[4];
        #pragma unroll
        for (int t = 0; t < 4; t++) af[t]  = *(const s16x8*)&As[(wr + t*16 + l16) * 32 + quad * 8];
        #pragma unroll
        for (int t = 0; t < 4; t++) bfr[t] = *(const s16x8*)&Bs[(wc + t*16 + l16) * 32 + quad * 8];
        #pragma unroll
        for (int i = 0; i < 4; i++)
            #pragma unroll
            for (int j = 0; j < 4; j++)
                acc[i][j] = MFMA16(af[i], bfr[j], acc[i][j]);
    }

    // C/D layout (m89-verified): row(m) = quad*4 + r, col(n) = l16
    short* dst = (sel == 0) ? qproj : ((sel == 1) ? kproj : vproj);
    const float* bp = (sel == 0) ? bq : ((sel == 2) ? bv : nullptr);
    const int coff = sel << 10;
    #pragma unroll
    for (int j = 0; j < 4; j++){
        int c = n0 + wc + j * 16 + l16 - coff;
        float bb = bp ? bp[c] : 0.0f;
        #pragma unroll
        for (int i = 0; i < 4; i++){
            int row = m0 + wr + i * 16 + quad * 4;
            #pragma unroll
            for (int r = 0; r < 4; r++)
                dst[(size_t)(row + r) * C_ + c] = f2b(acc[i][j][r] + bb);
        }
    }
}

// ---------------- final projection + bias + residual (f32 out) ----------------
__global__ __launch_bounds__(256, 2) void gemm_out(
    const short* __restrict__ A, const short* __restrict__ W,
    const float* __restrict__ bias, const float* __restrict__ resid,
    float* __restrict__ outf)
{
    __shared__ short As[128 * 32];
    __shared__ short Bs[128 * 32];
    const int n0 = blockIdx.x * 128, m0 = blockIdx.y * 128;
    const int tid = threadIdx.x, lane = tid & 63, wave = tid >> 6;
    const int quad = lane >> 4, l16 = lane & 15;
    const int wr = (wave >> 1) * 64, wc = (wave & 1) * 64;
    const int srow = lane >> 2, scol = (lane & 3) * 8;

    f32x4 acc[4][4] = {};
    const short* Ag = A + (size_t)(m0 + wave * 32 + srow) * C_ + scol;
    const short* Bg = W + (size_t)(n0 + wave * 32 + srow) * C_ + scol;
    short* lA0 = As + (wave * 32) * 32;
    short* lA1 = As + (wave * 32 + 16) * 32;
    short* lB0 = Bs + (wave * 32) * 32;
    short* lB1 = Bs + (wave * 32 + 16) * 32;

    for (int k0 = 0; k0 < C_; k0 += 32){
        __syncthreads();
        gl_lds16(Ag + k0, lA0);
        gl_lds16(Ag + k0 + 16 * (size_t)C_, lA1);
        gl_lds16(Bg + k0, lB0);
        gl_lds16(Bg + k0 + 16 * (size_t)C_, lB1);
        __syncthreads();
        s16x8 af[4], bfr[4];
        #pragma unroll
        for (int t = 0; t < 4; t++) af[t]  = *(const s16x8*)&As[(wr + t*16 + l16) * 32 + quad * 8];
        #pragma unroll
        for (int t = 0; t < 4; t++) bfr[t] = *(const s16x8*)&Bs[(wc + t*16 + l16) * 32 + quad * 8];
        #pragma unroll
        for (int i = 0; i < 4; i++)
            #pragma unroll
            for (int j = 0; j < 4; j++)
                acc[i][j] = MFMA16(af[i], bfr[j], acc[i][j]);
    }

    #pragma unroll
    for (int j = 0; j < 4; j++){
        int c = n0 + wc + j * 16 + l16;
        float bb = bias[c];
        #pragma unroll
        for (int i = 0; i < 4; i++){
            int row = m0 + wr + i * 16 + quad * 4;
            #pragma unroll
            for (int r = 0; r < 4; r++){
                size_t idx = (size_t)(row + r) * C_ + c;
                outf[idx] = acc[i][j][r] + bb + resid[idx];
            }
        }
    }
}

// ---------------- RoPE (in place, bf16), q additionally scaled by D^-0.5 * log2(e) ---
__global__ void rope_kernel(short* __restrict__ q, short* __restrict__ k,
                            const int* __restrict__ qpos, const int* __restrict__ kpos){
    const int QP = B_ * N_ * H_ * 32;           // 2M q pairs
    int idx = blockIdx.x * blockDim.x + threadIdx.x;
    if (idx >= 2 * QP) return;
    bool isK = idx >= QP;
    int t = isK ? idx - QP : idx;
    int i = t & 31;
    int h = (t >> 5) & (H_ - 1);
    int row = t >> 9;                            // b*N + n
    int pos = isK ? kpos[row] : qpos[row];
    short* base = (isK ? k : q) + (size_t)row * C_ + h * D_;
    float x1 = b2f(base[i]), x2 = b2f(base[i + 32]);
    float invf = exp2f((float)i * (-13.287712379549449f / 32.0f));
    float f = (float)pos * invf;
    float c = cosf(f), s = sinf(f);
    float o1 = x1 * c - x2 * s;
    float o2 = x2 * c + x1 * s;
    float fac = isK ? 1.0f : (0.125f * 1.4426950408889634f);  // fold scale*log2e into q
    base[i]      = f2b(o1 * fac);
    base[i + 32] = f2b(o2 * fac);
}

// ---------------- V transpose: [B,M,H*D] -> [B,H,D,M] ----------------
__global__ void transpose_v(const short* __restrict__ v, short* __restrict__ vt){
    __shared__ short tile[64][72];
    int b = blockIdx.y >> 4, h = blockIdx.y & 15, mt = blockIdx.x;
    int tid = threadIdx.x;
    for (int c = tid; c < 512; c += 256){
        int m = c >> 3, d8 = (c & 7) * 8;
        *(s16x8*)&tile[m][d8] =
            *(const s16x8*)&v[((size_t)(b * M_ + mt * 64 + m)) * C_ + h * D_ + d8];
    }
    __syncthreads();
    for (int c = tid; c < 512; c += 256){
        int d = c >> 3, m8 = (c & 7) * 8;
        s16x8 o;
        #pragma unroll
        for (int jj = 0; jj < 8; jj++) o[jj] = tile[m8 + jj][d];
        *(s16x8*)&vt[(((size_t)(b * H_ + h)) * D_ + d) * M_ + mt * 64 + m8] = o;
    }
}

// ---------------- Flash attention (32x32x16 MFMA, S^T trick) ----------------
__global__ __launch_bounds__(256, 2) void flash_attn(
    const short* __restrict__ q, const short* __restrict__ k,
    const short* __restrict__ vt, short* __restrict__ o)
{
    // shorts: K[2] @0 (2*64*68), V[2] @8704, Ps @17408 (4 * 64*36), Lsum/Linv @26624
    __shared__ short smem[27136];
    const int b = blockIdx.y >> 4, h = blockIdx.y & 15;
    const int n0 = blockIdx.x * 128;
    const int tid = threadIdx.x, lane = tid & 63, wave = tid >> 6;
    const int hi = lane >> 5, l32 = lane & 31;
    const int wq = wave & 1, kq = wave >> 1;

    // Q fragments in registers (B-operand: B[k=d][n=query])
    s16x8 qf[2][4];
    #pragma unroll
    for (int qt = 0; qt < 2; qt++)
        #pragma unroll
        for (int c = 0; c < 4; c++)
            qf[qt][c] = *(const s16x8*)&q[((size_t)(b * N_ + n0 + wq * 64 + qt * 32 + l32)) * C_
                                          + h * D_ + c * 16 + hi * 8];

    const short* kg = k  + (size_t)(b * M_) * C_ + h * D_;
    const short* vg = vt + ((size_t)(b * H_ + h)) * D_ * M_;
    const int srow0 = tid >> 3, sseg = (tid & 7) * 8;

    union V8 { s16x8 v; uint2 u[2]; };
    V8 kreg[2], vreg[2];

    #pragma unroll
    for (int ii = 0; ii < 2; ii++){
        int row = srow0 + 32 * ii;
        kreg[ii].v = *(const s16x8*)&kg[(size_t)row * C_ + sseg];
        vreg[ii].v = *(const s16x8*)&vg[(size_t)row * M_ + sseg];
    }
    #pragma unroll
    for (int ii = 0; ii < 2; ii++){
        int row = srow0 + 32 * ii;
        short* kd = &smem[row * 68 + sseg];
        *(uint2*)kd = kreg[ii].u[0]; *(uint2*)(kd + 4) = kreg[ii].u[1];
        short* vd = &smem[8704 + row * 68 + sseg];
        *(uint2*)vd = vreg[ii].u[0]; *(uint2*)(vd + 4) = vreg[ii].u[1];
    }

    f32x16 zero16 = {};
    f32x16 oacc[2][2] = {zero16, zero16, zero16, zero16};
    float lacc[2] = {0.f, 0.f};
    short* Pw = &smem[17408 + wave * 2304];

    for (int st = 0; st < 32; st++){
        const int p = st & 1;
        __syncthreads();
        if (st < 31){
            #pragma unroll
            for (int ii = 0; ii < 2; ii++){
                int row = srow0 + 32 * ii;
                kreg[ii].v = *(const s16x8*)&kg[((size_t)((st + 1) * 64 + row)) * C_ + sseg];
                vreg[ii].v = *(const s16x8*)&vg[(size_t)row * M_ + (st + 1) * 64 + sseg];
            }
        }
        const short* Kp = &smem[p * 4352];
        const short* Vp = &smem[8704 + p * 4352];

        s16x4 kf[4][2];
        #pragma unroll
        for (int c = 0; c < 4; c++){
            const short* a = &Kp[(kq * 32 + l32) * 68 + c * 16 + hi * 8];
            kf[c][0] = *(const s16x4*)a; kf[c][1] = *(const s16x4*)(a + 4);
        }
        #pragma unroll
        for (int qt = 0; qt < 2; qt++){
            f32x16 sv = {};
            #pragma unroll
            for (int c = 0; c < 4; c++){
                s16x8 ka = __builtin_shufflevector(kf[c][0], kf[c][1], 0,1,2,3,4,5,6,7);
                sv = MFMA32(ka, qf[qt][c], sv);
            }
            float ls = 0.f;
            unsigned pb[8];
            #pragma unroll
            for (int g = 0; g < 4; g++){
                float p0 = __builtin_amdgcn_exp2f(sv[4*g+0]);
                float p1 = __builtin_amdgcn_exp2f(sv[4*g+1]);
                float p2 = __builtin_amdgcn_exp2f(sv[4*g+2]);
                float p3 = __builtin_amdgcn_exp2f(sv[4*g+3]);
                ls += (p0 + p1) + (p2 + p3);
                pb[2*g]   = __builtin_amdgcn_perm(fbits(p1), fbits(p0), 0x07060302);
                pb[2*g+1] = __builtin_amdgcn_perm(fbits(p3), fbits(p2), 0x07060302);
            }
            lacc[qt] += ls;
            #pragma unroll
            for (int g = 0; g < 4; g++){
                short* d = &Pw[(qt * 32 + l32) * 36 + 8 * g + 4 * hi];
                uint2 u; u.x = pb[2*g]; u.y = pb[2*g+1];
                *(uint2*)d = u;
            }
        }
        asm volatile("s_waitcnt lgkmcnt(0)" ::: "memory");

        // PV: O[q][d] += P(64x32) . V(32x64)
        s16x8 pf[2][2], vf[2][2];
        #pragma unroll
        for (int qt = 0; qt < 2; qt++)
            #pragma unroll
            for (int c = 0; c < 2; c++){
                const short* a = &Pw[(qt * 32 + l32) * 36 + c * 16 + hi * 8];
                pf[qt][c] = __builtin_shufflevector(*(const s16x4*)a, *(const s16x4*)(a + 4),
                                                    0,1,2,3,4,5,6,7);
            }
        #pragma unroll
        for (int dt = 0; dt < 2; dt++)
            #pragma unroll
            for (int c = 0; c < 2; c++){
                const short* a = &Vp[(dt * 32 + l32) * 68 + kq * 32 + c * 16 + hi * 8];
                vf[dt][c] = __builtin_shufflevector(*(const s16x4*)a, *(const s16x4*)(a + 4),
                                                    0,1,2,3,4,5,6,7);
            }
        #pragma unroll
        for (int qt = 0; qt < 2; qt++)
            #pragma unroll
            for (int dt = 0; dt < 2; dt++)
                #pragma unroll
                for (int c = 0; c < 2; c++)
                    oacc[qt][dt] = MFMA32(pf[qt][c], vf[dt][c], oacc[qt][dt]);

        __syncthreads();
        if (st < 31){
            int pn = p ^ 1;
            #pragma unroll
            for (int ii = 0; ii < 2; ii++){
                int row = srow0 + 32 * ii;
                short* kd = &smem[pn * 4352 + row * 68 + sseg];
                *(uint2*)kd = kreg[ii].u[0]; *(uint2*)(kd + 4) = kreg[ii].u[1];
                short* vd = &smem[8704 + pn * 4352 + row * 68 + sseg];
                *(uint2*)vd = vreg[ii].u[0]; *(uint2*)(vd + 4) = vreg[ii].u[1];
            }
        }
    }

    __syncthreads();   // everyone done with K/V/P buffers

    float* LO   = (float*)smem;            // [128][65] f32 (overlays K/V bufs)
    float* Lsum = (float*)&smem[26624];    // 128 f32
    float* Linv = Lsum + 128;              // 128 f32

    float l0[2];
    #pragma unroll
    for (int qt = 0; qt < 2; qt++)
        l0[qt] = lacc[qt] + __shfl_xor(lacc[qt], 32);

    if (kq == 1){
        #pragma unroll
        for (int qt = 0; qt < 2; qt++)
            Lsum[wq * 64 + qt * 32 + l32] = l0[qt];
        #pragma unroll
        for (int qt = 0; qt < 2; qt++)
            #pragma unroll
            for (int dt = 0; dt < 2; dt++)
                #pragma unroll
                for (int e = 0; e < 16; e++){
                    int qrow = wq * 64 + qt * 32 + (e & 3) + 8 * (e >> 2) + 4 * hi;
                    LO[qrow * 65 + dt * 32 + l32] = oacc[qt][dt][e];
                }
    }
    __syncthreads();
    if (kq == 0){
        #pragma unroll
        for (int qt = 0; qt < 2; qt++){
            float lt = l0[qt] + Lsum[wq * 64 + qt * 32 + l32];
            Linv[wq * 64 + qt * 32 + l32] = 1.0f / lt;
        }
        asm volatile("s_waitcnt lgkmcnt(0)" ::: "memory");
        #pragma unroll
        for (int qt = 0; qt < 2; qt++)
            #pragma unroll
            for (int dt = 0; dt < 2; dt++)
                #pragma unroll
                for (int e = 0; e < 16; e++){
                    int qrow = wq * 64 + qt * 32 + (e & 3) + 8 * (e >> 2) + 4 * hi;
                    float val = (oacc[qt][dt][e] + LO[qrow * 65 + dt * 32 + l32]) * Linv[qrow];
                    o[((size_t)(b * N_ + n0 + qrow)) * C_ + h * D_ + dt * 32 + l32] = f2b(val);
                }
    }
}

extern "C" void kernel_launch(void* const* d_in, const int* in_sizes, int n_in,
                              void* d_out, int out_size, void* d_ws, size_t ws_size,
                              hipStream_t stream) {
    const float* query = (const float*)d_in[0];
    const float* key   = (const float*)d_in[1];
    const int*   qpos  = (const int*)d_in[2];
    const int*   kpos  = (const int*)d_in[3];
    const float* Wq    = (const float*)d_in[4];
    const float* bq    = (const float*)d_in[5];
    const float* Wk    = (const float*)d_in[6];
    const float* Wv    = (const float*)d_in[7];
    const float* bv    = (const float*)d_in[8];
    const float* Wo    = (const float*)d_in[9];
    const float* bo    = (const float*)d_in[10];
    float* out = (float*)d_out;

    const size_t E4M = (size_t)4 * 1024 * 1024;
    const size_t E1M = (size_t)1024 * 1024;
    short* ws    = (short*)d_ws;
    short* qbf   = ws;                    // 4M (dead after proj -> reused as vT)
    short* kbf   = qbf   + E4M;           // 4M (dead after proj -> reused as attn)
    short* wqkvb = kbf   + E4M;           // 3M = [Wq;Wk;Wv]
    short* wob   = wqkvb + 3 * E1M;       // 1M
    short* qproj = wob   + E1M;           // 4M
    short* kproj = qproj + E4M;           // 4M
    short* vproj = kproj + E4M;           // 4M  -> total 24M shorts = 48 MB
    short* vT    = qbf;                   // alias
    short* attn  = kbf;                   // alias

    // 1) fused converts (12M elements, contiguous dst)
    cvt_all<<<6144, 256, 0, stream>>>(query, key, Wq, Wk, Wv, Wo, ws);

    // 2) fused QKV projection (plain epilogue; RoPE/transpose separate)
    gemm_qkv<<<dim3(24, 32), 256, 0, stream>>>(qbf, kbf, wqkvb, bq, bv,
                                               qproj, kproj, vproj);

    // 3) RoPE on q (with scale*log2e fold) and k, in place
    rope_kernel<<<(2 * B_ * N_ * H_ * 32) / 256, 256, 0, stream>>>(qproj, kproj, qpos, kpos);

    // 4) V -> V^T [B,H,D,M]
    transpose_v<<<dim3(M_ / 64, B_ * H_), 256, 0, stream>>>(vproj, vT);

    // 5) flash attention -> attn [B,N,C] bf16
    flash_attn<<<dim3(16, 32), 256, 0, stream>>>(qproj, kproj, vT, attn);

    // 6) output projection + bias + residual -> f32 out
    gemm_out<<<dim3(8, 32), 256, 0, stream>>>(attn, wob, bo, query, out);
}

// Round 4
// 235.369 us; speedup vs baseline: 2.8458x; 1.0004x over previous
//
#include <hip/hip_runtime.h>
#include <hip/hip_bf16.h>
#include <stdint.h>

#define B_ 2
#define N_ 2048
#define M_ 2048
#define C_ 1024
#define H_ 16
#define D_ 64

typedef __attribute__((ext_vector_type(8))) short s16x8;
typedef __attribute__((ext_vector_type(4))) short s16x4;
typedef __attribute__((ext_vector_type(4))) float f32x4;
typedef __attribute__((ext_vector_type(16))) float f32x16;

__device__ __attribute__((always_inline)) inline short f2b(float f){
    __hip_bfloat16 h = __float2bfloat16(f); short s; __builtin_memcpy(&s, &h, 2); return s;
}
__device__ __attribute__((always_inline)) inline float b2f(short s){
    __hip_bfloat16 h; __builtin_memcpy(&h, &s, 2); return __bfloat162float(h);
}

#define MFMA16(a,b,c) __builtin_amdgcn_mfma_f32_16x16x32_bf16(a,b,c,0,0,0)
#define MFMA32(a,b,c) __builtin_amdgcn_mfma_f32_32x32x16_bf16(a,b,c,0,0,0)

__device__ __attribute__((always_inline)) inline void gl_lds16(const void* g, void* l){
    __builtin_amdgcn_global_load_lds((__attribute__((address_space(1))) void*)g,
                                     (__attribute__((address_space(3))) void*)l, 16, 0, 0);
}
__device__ __attribute__((always_inline)) inline unsigned fbits(float f){
    unsigned u; __builtin_memcpy(&u, &f, 4); return u;
}

// ---------------- fused f32 -> bf16 convert: [query|key|Wq|Wk|Wv|Wo] -> ws[0..12M) ----
__global__ void cvt_all(const float* __restrict__ q, const float* __restrict__ k,
                        const float* __restrict__ wq, const float* __restrict__ wk,
                        const float* __restrict__ wv, const float* __restrict__ wo,
                        short* __restrict__ dst){
    long i = ((long)blockIdx.x * 256 + threadIdx.x) * 8;
    const float* src; long off;
    if      (i <  4194304L){ src = q;  off = i; }
    else if (i <  8388608L){ src = k;  off = i - 4194304L; }
    else if (i <  9437184L){ src = wq; off = i - 8388608L; }
    else if (i < 10485760L){ src = wk; off = i - 9437184L; }
    else if (i < 11534336L){ src = wv; off = i - 10485760L; }
    else                   { src = wo; off = i - 11534336L; }
    float4 a = *(const float4*)(src + off);
    float4 b = *(const float4*)(src + off + 4);
    s16x8 o;
    o[0]=f2b(a.x); o[1]=f2b(a.y); o[2]=f2b(a.z); o[3]=f2b(a.w);
    o[4]=f2b(b.x); o[5]=f2b(b.y); o[6]=f2b(b.z); o[7]=f2b(b.w);
    *(s16x8*)(dst + i) = o;
}

// ---------------- fused QKV projection GEMM (plain epilogue) --------
// A = qbf (n0<1024) or kbf; W = [Wq;Wk;Wv] (3072,1024) bf16 row-major.
// launch_bounds(256,3): 768 blocks -> exactly 1 round at 3 blocks/CU (~155 VGPR est).
__global__ __launch_bounds__(256, 3) void gemm_qkv(
    const short* __restrict__ qbf, const short* __restrict__ kbf,
    const short* __restrict__ W,
    const float* __restrict__ bq, const float* __restrict__ bv,
    short* __restrict__ qproj, short* __restrict__ kproj, short* __restrict__ vproj)
{
    __shared__ short As[128 * 32];
    __shared__ short Bs[128 * 32];
    const int n0 = blockIdx.x * 128, m0 = blockIdx.y * 128;
    const int sel = n0 >> 10;                 // 0=q, 1=k, 2=v (block-uniform)
    const short* A = (sel == 0) ? qbf : kbf;
    const int tid = threadIdx.x, lane = tid & 63, wave = tid >> 6;
    const int quad = lane >> 4, l16 = lane & 15;
    const int wr = (wave >> 1) * 64, wc = (wave & 1) * 64;
    const int srow = lane >> 2, scol = (lane & 3) * 8;

    f32x4 acc[4][4] = {};

    const short* Ag = A + (size_t)(m0 + wave * 32 + srow) * C_ + scol;
    const short* Bg = W + (size_t)(n0 + wave * 32 + srow) * C_ + scol;
    short* lA0 = As + (wave * 32) * 32;
    short* lA1 = As + (wave * 32 + 16) * 32;
    short* lB0 = Bs + (wave * 32) * 32;
    short* lB1 = Bs + (wave * 32 + 16) * 32;

    for (int k0 = 0; k0 < C_; k0 += 32){
        __syncthreads();
        gl_lds16(Ag + k0, lA0);
        gl_lds16(Ag + k0 + 16 * (size_t)C_, lA1);
        gl_lds16(Bg + k0, lB0);
        gl_lds16(Bg + k0 + 16 * (size_t)C_, lB1);
        __syncthreads();
        s16x8 af[4], bfr[4];
        #pragma unroll
        for (int t = 0; t < 4; t++) af[t]  = *(const s16x8*)&As[(wr + t*16 + l16) * 32 + quad * 8];
        #pragma unroll
        for (int t = 0; t < 4; t++) bfr[t] = *(const s16x8*)&Bs[(wc + t*16 + l16) * 32 + quad * 8];
        #pragma unroll
        for (int i = 0; i < 4; i++)
            #pragma unroll
            for (int j = 0; j < 4; j++)
                acc[i][j] = MFMA16(af[i], bfr[j], acc[i][j]);
    }

    short* dst = (sel == 0) ? qproj : ((sel == 1) ? kproj : vproj);
    const float* bp = (sel == 0) ? bq : ((sel == 2) ? bv : nullptr);
    const int coff = sel << 10;
    #pragma unroll
    for (int j = 0; j < 4; j++){
        int c = n0 + wc + j * 16 + l16 - coff;
        float bb = bp ? bp[c] : 0.0f;
        #pragma unroll
        for (int i = 0; i < 4; i++){
            int row = m0 + wr + i * 16 + quad * 4;
            #pragma unroll
            for (int r = 0; r < 4; r++)
                dst[(size_t)(row + r) * C_ + c] = f2b(acc[i][j][r] + bb);
        }
    }
}

// ---------------- final projection + bias + residual (f32 out) ----------------
// 128m x 64n tiles -> 512 blocks; acc 32 VGPR -> launch_bounds(256,4).
__global__ __launch_bounds__(256, 4) void gemm_out(
    const short* __restrict__ A, const short* __restrict__ W,
    const float* __restrict__ bias, const float* __restrict__ resid,
    float* __restrict__ outf)
{
    __shared__ short As[128 * 32];
    __shared__ short Bs[64 * 32];
    const int n0 = blockIdx.x * 64, m0 = blockIdx.y * 128;
    const int tid = threadIdx.x, lane = tid & 63, wave = tid >> 6;
    const int quad = lane >> 4, l16 = lane & 15;
    const int srow = lane >> 2, scol = (lane & 3) * 8;
    const int srowB = lane >> 2;      // 16 rows per wave for B

    f32x4 acc[2][4] = {};
    const short* Ag = A + (size_t)(m0 + wave * 32 + srow) * C_ + scol;
    const short* Bg = W + (size_t)(n0 + wave * 16 + srowB) * C_ + scol;
    short* lA0 = As + (wave * 32) * 32;
    short* lA1 = As + (wave * 32 + 16) * 32;
    short* lB  = Bs + (wave * 16) * 32;

    for (int k0 = 0; k0 < C_; k0 += 32){
        __syncthreads();
        gl_lds16(Ag + k0, lA0);
        gl_lds16(Ag + k0 + 16 * (size_t)C_, lA1);
        gl_lds16(Bg + k0, lB);
        __syncthreads();
        s16x8 af[2], bfr[4];
        #pragma unroll
        for (int t = 0; t < 2; t++) af[t]  = *(const s16x8*)&As[(wave*32 + t*16 + l16) * 32 + quad * 8];
        #pragma unroll
        for (int t = 0; t < 4; t++) bfr[t] = *(const s16x8*)&Bs[(t*16 + l16) * 32 + quad * 8];
        #pragma unroll
        for (int i = 0; i < 2; i++)
            #pragma unroll
            for (int j = 0; j < 4; j++)
                acc[i][j] = MFMA16(af[i], bfr[j], acc[i][j]);
    }

    #pragma unroll
    for (int j = 0; j < 4; j++){
        int c = n0 + j * 16 + l16;
        float bb = bias[c];
        #pragma unroll
        for (int i = 0; i < 2; i++){
            int row = m0 + wave * 32 + i * 16 + quad * 4;
            #pragma unroll
            for (int r = 0; r < 4; r++){
                size_t idx = (size_t)(row + r) * C_ + c;
                outf[idx] = acc[i][j][r] + bb + resid[idx];
            }
        }
    }
}

// ---------------- RoPE (in place, bf16), q additionally scaled by D^-0.5 * log2(e) ---
__global__ void rope_kernel(short* __restrict__ q, short* __restrict__ k,
                            const int* __restrict__ qpos, const int* __restrict__ kpos){
    const int QP = B_ * N_ * H_ * 32;           // 2M q pairs
    int idx = blockIdx.x * blockDim.x + threadIdx.x;
    if (idx >= 2 * QP) return;
    bool isK = idx >= QP;
    int t = isK ? idx - QP : idx;
    int i = t & 31;
    int h = (t >> 5) & (H_ - 1);
    int row = t >> 9;                            // b*N + n
    int pos = isK ? kpos[row] : qpos[row];
    short* base = (isK ? k : q) + (size_t)row * C_ + h * D_;
    float x1 = b2f(base[i]), x2 = b2f(base[i + 32]);
    float invf = exp2f((float)i * (-13.287712379549449f / 32.0f));
    float f = (float)pos * invf;
    float c = cosf(f), s = sinf(f);
    float o1 = x1 * c - x2 * s;
    float o2 = x2 * c + x1 * s;
    float fac = isK ? 1.0f : (0.125f * 1.4426950408889634f);  // fold scale*log2e into q
    base[i]      = f2b(o1 * fac);
    base[i + 32] = f2b(o2 * fac);
}

// ---------------- V transpose: [B,M,H*D] -> [B,H,D,M] ----------------
__global__ void transpose_v(const short* __restrict__ v, short* __restrict__ vt){
    __shared__ short tile[64][72];
    int b = blockIdx.y >> 4, h = blockIdx.y & 15, mt = blockIdx.x;
    int tid = threadIdx.x;
    for (int c = tid; c < 512; c += 256){
        int m = c >> 3, d8 = (c & 7) * 8;
        *(s16x8*)&tile[m][d8] =
            *(const s16x8*)&v[((size_t)(b * M_ + mt * 64 + m)) * C_ + h * D_ + d8];
    }
    __syncthreads();
    for (int c = tid; c < 512; c += 256){
        int d = c >> 3, m8 = (c & 7) * 8;
        s16x8 o;
        #pragma unroll
        for (int jj = 0; jj < 8; jj++) o[jj] = tile[m8 + jj][d];
        *(s16x8*)&vt[(((size_t)(b * H_ + h)) * D_ + d) * M_ + mt * 64 + m8] = o;
    }
}

// ---------------- Flash attention (64-q-row blocks, 32x32x16 MFMA, S^T trick) -------
// Grid 1024 blocks; LDS 44.5 KB -> 3 blocks/CU (12 waves/CU). 4 waves =
// wq (2 q-strips of 32) x kq (2 key-halves of the 64-key stage).
__global__ __launch_bounds__(256, 3) void flash_attn(
    const short* __restrict__ q, const short* __restrict__ k,
    const short* __restrict__ vt, short* __restrict__ o)
{
    // shorts: K[2] @0 (2*64*68=8704), V[2] @8704, Ps @17408 (4*32*36=4608), L @22016
    __shared__ short smem[22272];
    const int b = blockIdx.y >> 4, h = blockIdx.y & 15;
    const int n0 = blockIdx.x * 64;
    const int tid = threadIdx.x, lane = tid & 63, wave = tid >> 6;
    const int hi = lane >> 5, l32 = lane & 31;
    const int wq = wave & 1, kq = wave >> 1;

    // Q fragments in registers (B-operand: lane n = q row, k = d)
    s16x8 qf[4];
    #pragma unroll
    for (int c = 0; c < 4; c++)
        qf[c] = *(const s16x8*)&q[((size_t)(b * N_ + n0 + wq * 32 + l32)) * C_
                                  + h * D_ + c * 16 + hi * 8];

    const short* kg = k  + (size_t)(b * M_) * C_ + h * D_;
    const short* vg = vt + ((size_t)(b * H_ + h)) * D_ * M_;
    const int srow0 = tid >> 3, sseg = (tid & 7) * 8;

    union V8 { s16x8 v; uint2 u[2]; };
    V8 kreg[2], vreg[2];

    #pragma unroll
    for (int ii = 0; ii < 2; ii++){
        int row = srow0 + 32 * ii;
        kreg[ii].v = *(const s16x8*)&kg[(size_t)row * C_ + sseg];
        vreg[ii].v = *(const s16x8*)&vg[(size_t)row * M_ + sseg];
    }
    #pragma unroll
    for (int ii = 0; ii < 2; ii++){
        int row = srow0 + 32 * ii;
        short* kd = &smem[row * 68 + sseg];
        *(uint2*)kd = kreg[ii].u[0]; *(uint2*)(kd + 4) = kreg[ii].u[1];
        short* vd = &smem[8704 + row * 68 + sseg];
        *(uint2*)vd = vreg[ii].u[0]; *(uint2*)(vd + 4) = vreg[ii].u[1];
    }

    f32x16 zero16 = {};
    f32x16 oacc[2] = {zero16, zero16};
    float lacc = 0.f;
    short* Pw = &smem[17408 + wave * 1152];

    for (int st = 0; st < 32; st++){
        const int p = st & 1;
        __syncthreads();
        if (st < 31){
            #pragma unroll
            for (int ii = 0; ii < 2; ii++){
                int row = srow0 + 32 * ii;
                kreg[ii].v = *(const s16x8*)&kg[((size_t)((st + 1) * 64 + row)) * C_ + sseg];
                vreg[ii].v = *(const s16x8*)&vg[(size_t)row * M_ + (st + 1) * 64 + sseg];
            }
        }
        const short* Kp = &smem[p * 4352];
        const short* Vp = &smem[8704 + p * 4352];

        // K A-frags for this wave's 32-key strip
        s16x4 kf[4][2];
        #pragma unroll
        for (int c = 0; c < 4; c++){
            const short* a = &Kp[(kq * 32 + l32) * 68 + c * 16 + hi * 8];
            kf[c][0] = *(const s16x4*)a; kf[c][1] = *(const s16x4*)(a + 4);
        }
        // S^T = K . Q^T  (C rows = key, cols = q)
        f32x16 sv = {};
        #pragma unroll
        for (int c = 0; c < 4; c++){
            s16x8 ka = __builtin_shufflevector(kf[c][0], kf[c][1], 0,1,2,3,4,5,6,7);
            sv = MFMA32(ka, qf[c], sv);
        }
        float ls = 0.f;
        unsigned pb[8];
        #pragma unroll
        for (int g = 0; g < 4; g++){
            float p0 = __builtin_amdgcn_exp2f(sv[4*g+0]);
            float p1 = __builtin_amdgcn_exp2f(sv[4*g+1]);
            float p2 = __builtin_amdgcn_exp2f(sv[4*g+2]);
            float p3 = __builtin_amdgcn_exp2f(sv[4*g+3]);
            ls += (p0 + p1) + (p2 + p3);
            pb[2*g]   = __builtin_amdgcn_perm(fbits(p1), fbits(p0), 0x07060302);
            pb[2*g+1] = __builtin_amdgcn_perm(fbits(p3), fbits(p2), 0x07060302);
        }
        lacc += ls;
        #pragma unroll
        for (int g = 0; g < 4; g++){
            short* d = &Pw[l32 * 36 + 8 * g + 4 * hi];
            uint2 u; u.x = pb[2*g]; u.y = pb[2*g+1];
            *(uint2*)d = u;
        }
        asm volatile("s_waitcnt lgkmcnt(0)" ::: "memory");

        // PV: O[q=32][d=64] += P(32x32) . V(32x64)
        s16x8 pf[2], vf[2][2];
        #pragma unroll
        for (int c = 0; c < 2; c++){
            const short* a = &Pw[l32 * 36 + c * 16 + hi * 8];
            pf[c] = __builtin_shufflevector(*(const s16x4*)a, *(const s16x4*)(a + 4),
                                            0,1,2,3,4,5,6,7);
        }
        #pragma unroll
        for (int dt = 0; dt < 2; dt++)
            #pragma unroll
            for (int c = 0; c < 2; c++){
                const short* a = &Vp[(dt * 32 + l32) * 68 + kq * 32 + c * 16 + hi * 8];
                vf[dt][c] = __builtin_shufflevector(*(const s16x4*)a, *(const s16x4*)(a + 4),
                                                    0,1,2,3,4,5,6,7);
            }
        #pragma unroll
        for (int dt = 0; dt < 2; dt++)
            #pragma unroll
            for (int c = 0; c < 2; c++)
                oacc[dt] = MFMA32(pf[c], vf[dt][c], oacc[dt]);

        __syncthreads();
        if (st < 31){
            int pn = p ^ 1;
            #pragma unroll
            for (int ii = 0; ii < 2; ii++){
                int row = srow0 + 32 * ii;
                short* kd = &smem[pn * 4352 + row * 68 + sseg];
                *(uint2*)kd = kreg[ii].u[0]; *(uint2*)(kd + 4) = kreg[ii].u[1];
                short* vd = &smem[8704 + pn * 4352 + row * 68 + sseg];
                *(uint2*)vd = vreg[ii].u[0]; *(uint2*)(vd + 4) = vreg[ii].u[1];
            }
        }
    }

    __syncthreads();   // everyone done with K/V/P buffers

    float* LO   = (float*)smem;            // [64][65] f32 (overlays K buffers)
    float* Lsum = (float*)&smem[22016];    // 64 f32
    float* Linv = Lsum + 64;               // 64 f32

    float l0 = lacc + __shfl_xor(lacc, 32);

    if (kq == 1){
        Lsum[wq * 32 + l32] = l0;
        #pragma unroll
        for (int dt = 0; dt < 2; dt++)
            #pragma unroll
            for (int e = 0; e < 16; e++){
                int qrow = wq * 32 + (e & 3) + 8 * (e >> 2) + 4 * hi;
                LO[qrow * 65 + dt * 32 + l32] = oacc[dt][e];
            }
    }
    __syncthreads();
    if (kq == 0){
        float lt = l0 + Lsum[wq * 32 + l32];
        Linv[wq * 32 + l32] = 1.0f / lt;
        asm volatile("s_waitcnt lgkmcnt(0)" ::: "memory");
        #pragma unroll
        for (int dt = 0; dt < 2; dt++)
            #pragma unroll
            for (int e = 0; e < 16; e++){
                int qrow = wq * 32 + (e & 3) + 8 * (e >> 2) + 4 * hi;
                float val = (oacc[dt][e] + LO[qrow * 65 + dt * 32 + l32]) * Linv[qrow];
                o[((size_t)(b * N_ + n0 + qrow)) * C_ + h * D_ + dt * 32 + l32] = f2b(val);
            }
    }
}

extern "C" void kernel_launch(void* const* d_in, const int* in_sizes, int n_in,
                              void* d_out, int out_size, void* d_ws, size_t ws_size,
                              hipStream_t stream) {
    const float* query = (const float*)d_in[0];
    const float* key   = (const float*)d_in[1];
    const int*   qpos  = (const int*)d_in[2];
    const int*   kpos  = (const int*)d_in[3];
    const float* Wq    = (const float*)d_in[4];
    const float* bq    = (const float*)d_in[5];
    const float* Wk    = (const float*)d_in[6];
    const float* Wv    = (const float*)d_in[7];
    const float* bv    = (const float*)d_in[8];
    const float* Wo    = (const float*)d_in[9];
    const float* bo    = (const float*)d_in[10];
    float* out = (float*)d_out;

    const size_t E4M = (size_t)4 * 1024 * 1024;
    const size_t E1M = (size_t)1024 * 1024;
    short* ws    = (short*)d_ws;
    short* qbf   = ws;                    // 4M (dead after proj -> reused as vT)
    short* kbf   = qbf   + E4M;           // 4M (dead after proj -> reused as attn)
    short* wqkvb = kbf   + E4M;           // 3M = [Wq;Wk;Wv]
    short* wob   = wqkvb + 3 * E1M;       // 1M
    short* qproj = wob   + E1M;           // 4M
    short* kproj = qproj + E4M;           // 4M
    short* vproj = kproj + E4M;           // 4M  -> total 24M shorts = 48 MB
    short* vT    = qbf;                   // alias
    short* attn  = kbf;                   // alias

    // 1) fused converts (12M elements, contiguous dst)
    cvt_all<<<6144, 256, 0, stream>>>(query, key, Wq, Wk, Wv, Wo, ws);

    // 2) fused QKV projection (plain epilogue)
    gemm_qkv<<<dim3(24, 32), 256, 0, stream>>>(qbf, kbf, wqkvb, bq, bv,
                                               qproj, kproj, vproj);

    // 3) RoPE on q (with scale*log2e fold) and k, in place
    rope_kernel<<<(2 * B_ * N_ * H_ * 32) / 256, 256, 0, stream>>>(qproj, kproj, qpos, kpos);

    // 4) V -> V^T [B,H,D,M]
    transpose_v<<<dim3(M_ / 64, B_ * H_), 256, 0, stream>>>(vproj, vT);

    // 5) flash attention -> attn [B,N,C] bf16
    flash_attn<<<dim3(32, 32), 256, 0, stream>>>(qproj, kproj, vT, attn);

    // 6) output projection + bias + residual -> f32 out
    gemm_out<<<dim3(16, 32), 256, 0, stream>>>(attn, wob, bo, query, out);
}

// Round 5
// 212.647 us; speedup vs baseline: 3.1499x; 1.1069x over previous
//
#include <hip/hip_runtime.h>
#include <hip/hip_bf16.h>
#include <stdint.h>

#define B_ 2
#define N_ 2048
#define M_ 2048
#define C_ 1024
#define H_ 16
#define D_ 64

typedef __attribute__((ext_vector_type(8))) short s16x8;
typedef __attribute__((ext_vector_type(4))) short s16x4;
typedef __attribute__((ext_vector_type(4))) float f32x4;
typedef __attribute__((ext_vector_type(16))) float f32x16;

__device__ __attribute__((always_inline)) inline short f2b(float f){
    __hip_bfloat16 h = __float2bfloat16(f); short s; __builtin_memcpy(&s, &h, 2); return s;
}
__device__ __attribute__((always_inline)) inline float b2f(short s){
    __hip_bfloat16 h; __builtin_memcpy(&h, &s, 2); return __bfloat162float(h);
}

#define MFMA16(a,b,c) __builtin_amdgcn_mfma_f32_16x16x32_bf16(a,b,c,0,0,0)
#define MFMA32(a,b,c) __builtin_amdgcn_mfma_f32_32x32x16_bf16(a,b,c,0,0,0)

__device__ __attribute__((always_inline)) inline void gl_lds16(const void* g, void* l){
    __builtin_amdgcn_global_load_lds((__attribute__((address_space(1))) void*)g,
                                     (__attribute__((address_space(3))) void*)l, 16, 0, 0);
}
__device__ __attribute__((always_inline)) inline unsigned fbits(float f){
    unsigned u; __builtin_memcpy(&u, &f, 4); return u;
}

// ---------------- fused f32 -> bf16 convert: [query|key|Wq|Wk|Wv|Wo] -> ws[0..12M) ----
__global__ void cvt_all(const float* __restrict__ q, const float* __restrict__ k,
                        const float* __restrict__ wq, const float* __restrict__ wk,
                        const float* __restrict__ wv, const float* __restrict__ wo,
                        short* __restrict__ dst){
    long i = ((long)blockIdx.x * 256 + threadIdx.x) * 8;
    const float* src; long off;
    if      (i <  4194304L){ src = q;  off = i; }
    else if (i <  8388608L){ src = k;  off = i - 4194304L; }
    else if (i <  9437184L){ src = wq; off = i - 8388608L; }
    else if (i < 10485760L){ src = wk; off = i - 9437184L; }
    else if (i < 11534336L){ src = wv; off = i - 10485760L; }
    else                   { src = wo; off = i - 11534336L; }
    float4 a = *(const float4*)(src + off);
    float4 b = *(const float4*)(src + off + 4);
    s16x8 o;
    o[0]=f2b(a.x); o[1]=f2b(a.y); o[2]=f2b(a.z); o[3]=f2b(a.w);
    o[4]=f2b(b.x); o[5]=f2b(b.y); o[6]=f2b(b.z); o[7]=f2b(b.w);
    *(s16x8*)(dst + i) = o;
}

// ---------------- fused QKV projection GEMM ----------------
// A = qbf (n0<1024) or kbf; W = [Wq;Wk;Wv] (3072,1024) bf16 row-major.
// Epilogue: q -> +bq plain store; k -> plain store; v -> +bv stored transposed vT[b,h,d,m].
__global__ __launch_bounds__(256, 3) void gemm_qkv(
    const short* __restrict__ qbf, const short* __restrict__ kbf,
    const short* __restrict__ W,
    const float* __restrict__ bq, const float* __restrict__ bv,
    short* __restrict__ qproj, short* __restrict__ kproj, short* __restrict__ vT)
{
    __shared__ short As[128 * 32];
    __shared__ short Bs[128 * 32];
    const int n0 = blockIdx.x * 128, m0 = blockIdx.y * 128;
    const int sel = n0 >> 10;                 // 0=q, 1=k, 2=v (block-uniform)
    const short* A = (sel == 0) ? qbf : kbf;
    const int tid = threadIdx.x, lane = tid & 63, wave = tid >> 6;
    const int quad = lane >> 4, l16 = lane & 15;
    const int wr = (wave >> 1) * 64, wc = (wave & 1) * 64;
    const int srow = lane >> 2, scol = (lane & 3) * 8;

    f32x4 acc[4][4] = {};

    const short* Ag = A + (size_t)(m0 + wave * 32 + srow) * C_ + scol;
    const short* Bg = W + (size_t)(n0 + wave * 32 + srow) * C_ + scol;
    short* lA0 = As + (wave * 32) * 32;
    short* lA1 = As + (wave * 32 + 16) * 32;
    short* lB0 = Bs + (wave * 32) * 32;
    short* lB1 = Bs + (wave * 32 + 16) * 32;

    for (int k0 = 0; k0 < C_; k0 += 32){
        __syncthreads();
        gl_lds16(Ag + k0, lA0);
        gl_lds16(Ag + k0 + 16 * (size_t)C_, lA1);
        gl_lds16(Bg + k0, lB0);
        gl_lds16(Bg + k0 + 16 * (size_t)C_, lB1);
        __syncthreads();
        s16x8 af[4], bfr[4];
        #pragma unroll
        for (int t = 0; t < 4; t++) af[t]  = *(const s16x8*)&As[(wr + t*16 + l16) * 32 + quad * 8];
        #pragma unroll
        for (int t = 0; t < 4; t++) bfr[t] = *(const s16x8*)&Bs[(wc + t*16 + l16) * 32 + quad * 8];
        #pragma unroll
        for (int i = 0; i < 4; i++)
            #pragma unroll
            for (int j = 0; j < 4; j++)
                acc[i][j] = MFMA16(af[i], bfr[j], acc[i][j]);
    }

    // C/D layout (m89-verified): row(m) = quad*4 + r, col(n) = l16
    if (sel <= 1){
        short* dst = sel ? kproj : qproj;
        const float* bp = sel ? nullptr : bq;
        const int coff = sel << 10;
        #pragma unroll
        for (int j = 0; j < 4; j++){
            int c = n0 + wc + j * 16 + l16 - coff;
            float bb = bp ? bp[c] : 0.0f;
            #pragma unroll
            for (int i = 0; i < 4; i++){
                int row = m0 + wr + i * 16 + quad * 4;
                #pragma unroll
                for (int r = 0; r < 4; r++)
                    dst[(size_t)(row + r) * C_ + c] = f2b(acc[i][j][r] + bb);
            }
        }
    } else {
        // V: +bv, store transposed as vT[b,h,d,m] (round-2-proven uint2 scatter)
        #pragma unroll
        for (int j = 0; j < 4; j++){
            int col = n0 - 2048 + wc + j * 16 + l16;            // 0..1023
            int h = col >> 6, d = col & 63;
            float bb = bv[col];
            #pragma unroll
            for (int i = 0; i < 4; i++){
                int row = m0 + wr + i * 16 + quad * 4;
                int b = row >> 11, m = row & 2047;
                unsigned u0 = (unsigned)(unsigned short)f2b(acc[i][j][0] + bb) |
                              ((unsigned)(unsigned short)f2b(acc[i][j][1] + bb) << 16);
                unsigned u1 = (unsigned)(unsigned short)f2b(acc[i][j][2] + bb) |
                              ((unsigned)(unsigned short)f2b(acc[i][j][3] + bb) << 16);
                uint2 u; u.x = u0; u.y = u1;
                *(uint2*)&vT[(((size_t)(b * H_ + h)) * D_ + d) * M_ + m] = u;
            }
        }
    }
}

// ---------------- final projection + bias + residual (f32 out) ----------------
// 128m x 64n tiles -> 512 blocks; acc 32 VGPR -> launch_bounds(256,4).
__global__ __launch_bounds__(256, 4) void gemm_out(
    const short* __restrict__ A, const short* __restrict__ W,
    const float* __restrict__ bias, const float* __restrict__ resid,
    float* __restrict__ outf)
{
    __shared__ short As[128 * 32];
    __shared__ short Bs[64 * 32];
    const int n0 = blockIdx.x * 64, m0 = blockIdx.y * 128;
    const int tid = threadIdx.x, lane = tid & 63, wave = tid >> 6;
    const int quad = lane >> 4, l16 = lane & 15;
    const int srow = lane >> 2, scol = (lane & 3) * 8;

    f32x4 acc[2][4] = {};
    const short* Ag = A + (size_t)(m0 + wave * 32 + srow) * C_ + scol;
    const short* Bg = W + (size_t)(n0 + wave * 16 + srow) * C_ + scol;
    short* lA0 = As + (wave * 32) * 32;
    short* lA1 = As + (wave * 32 + 16) * 32;
    short* lB  = Bs + (wave * 16) * 32;

    for (int k0 = 0; k0 < C_; k0 += 32){
        __syncthreads();
        gl_lds16(Ag + k0, lA0);
        gl_lds16(Ag + k0 + 16 * (size_t)C_, lA1);
        gl_lds16(Bg + k0, lB);
        __syncthreads();
        s16x8 af[2], bfr[4];
        #pragma unroll
        for (int t = 0; t < 2; t++) af[t]  = *(const s16x8*)&As[(wave*32 + t*16 + l16) * 32 + quad * 8];
        #pragma unroll
        for (int t = 0; t < 4; t++) bfr[t] = *(const s16x8*)&Bs[(t*16 + l16) * 32 + quad * 8];
        #pragma unroll
        for (int i = 0; i < 2; i++)
            #pragma unroll
            for (int j = 0; j < 4; j++)
                acc[i][j] = MFMA16(af[i], bfr[j], acc[i][j]);
    }

    #pragma unroll
    for (int j = 0; j < 4; j++){
        int c = n0 + j * 16 + l16;
        float bb = bias[c];
        #pragma unroll
        for (int i = 0; i < 2; i++){
            int row = m0 + wave * 32 + i * 16 + quad * 4;
            #pragma unroll
            for (int r = 0; r < 4; r++){
                size_t idx = (size_t)(row + r) * C_ + c;
                outf[idx] = acc[i][j][r] + bb + resid[idx];
            }
        }
    }
}

// ---------------- RoPE on K only (in place, bf16), native trig ----------------
__global__ void rope_k(short* __restrict__ k, const int* __restrict__ kpos){
    int t = blockIdx.x * blockDim.x + threadIdx.x;   // B*M*H*32 = 2M threads
    int i = t & 31;
    int h = (t >> 5) & (H_ - 1);
    int row = t >> 9;                                // b*M + m
    int pos = kpos[row];
    short* base = k + (size_t)row * C_ + h * D_;
    float x1 = b2f(base[i]), x2 = b2f(base[i + 32]);
    float invf = exp2f((float)i * (-13.287712379549449f / 32.0f));
    float f = (float)pos * invf;
    float c = __cosf(f), s = __sinf(f);
    base[i]      = f2b(x1 * c - x2 * s);
    base[i + 32] = f2b(x2 * c + x1 * s);
}

// ---------------- Flash attention (128-q blocks, 32x32x16 MFMA, S^T trick) ----------
// q-RoPE fused in prologue (reads raw qproj + qpos; applies rotation + scale*log2e).
__global__ __launch_bounds__(256, 2) void flash_attn(
    const short* __restrict__ q, const short* __restrict__ k,
    const short* __restrict__ vt, short* __restrict__ o,
    const int* __restrict__ qpos)
{
    // shorts: K[2] @0 (2*64*68), V[2] @8704, Ps @17408 (4 * 64*36), Lsum/Linv @26624
    __shared__ short smem[27136];
    const int b = blockIdx.y >> 4, h = blockIdx.y & 15;
    const int n0 = blockIdx.x * 128;
    const int tid = threadIdx.x, lane = tid & 63, wave = tid >> 6;
    const int hi = lane >> 5, l32 = lane & 31;
    const int wq = wave & 1, kq = wave >> 1;

    // Q fragments (B-operand: lane n = q row, k = d), with fused RoPE + scale*log2e
    s16x8 qf[2][4];
    const float fac = 0.18033688011112042f;   // 0.125 * log2(e)
    #pragma unroll
    for (int qt = 0; qt < 2; qt++){
        int qrow = n0 + wq * 64 + qt * 32 + l32;
        const short* qg = &q[((size_t)(b * N_ + qrow)) * C_ + h * D_];
        float pos = (float)qpos[b * N_ + qrow];
        s16x8 raw[4];
        #pragma unroll
        for (int c = 0; c < 4; c++) raw[c] = *(const s16x8*)&qg[c * 16 + hi * 8];
        #pragma unroll
        for (int c = 0; c < 2; c++){
            s16x8 olo, ohi8;
            #pragma unroll
            for (int j = 0; j < 8; j++){
                int irot = c * 16 + hi * 8 + j;
                float invf = exp2f((float)irot * (-13.287712379549449f / 32.0f));
                float ang = pos * invf;
                float cs = __cosf(ang), sn = __sinf(ang);
                float x1 = b2f(raw[c][j]), x2 = b2f(raw[c + 2][j]);
                olo[j]  = f2b((x1 * cs - x2 * sn) * fac);
                ohi8[j] = f2b((x2 * cs + x1 * sn) * fac);
            }
            qf[qt][c] = olo; qf[qt][c + 2] = ohi8;
        }
    }

    const short* kg = k  + (size_t)(b * M_) * C_ + h * D_;
    const short* vg = vt + ((size_t)(b * H_ + h)) * D_ * M_;
    const int srow0 = tid >> 3, sseg = (tid & 7) * 8;

    union V8 { s16x8 v; uint2 u[2]; };
    V8 kreg[2], vreg[2];

    #pragma unroll
    for (int ii = 0; ii < 2; ii++){
        int row = srow0 + 32 * ii;
        kreg[ii].v = *(const s16x8*)&kg[(size_t)row * C_ + sseg];
        vreg[ii].v = *(const s16x8*)&vg[(size_t)row * M_ + sseg];
    }
    #pragma unroll
    for (int ii = 0; ii < 2; ii++){
        int row = srow0 + 32 * ii;
        short* kd = &smem[row * 68 + sseg];
        *(uint2*)kd = kreg[ii].u[0]; *(uint2*)(kd + 4) = kreg[ii].u[1];
        short* vd = &smem[8704 + row * 68 + sseg];
        *(uint2*)vd = vreg[ii].u[0]; *(uint2*)(vd + 4) = vreg[ii].u[1];
    }

    f32x16 zero16 = {};
    f32x16 oacc[2][2] = {zero16, zero16, zero16, zero16};
    float lacc[2] = {0.f, 0.f};
    short* Pw = &smem[17408 + wave * 2304];

    for (int st = 0; st < 32; st++){
        const int p = st & 1;
        __syncthreads();
        if (st < 31){
            #pragma unroll
            for (int ii = 0; ii < 2; ii++){
                int row = srow0 + 32 * ii;
                kreg[ii].v = *(const s16x8*)&kg[((size_t)((st + 1) * 64 + row)) * C_ + sseg];
                vreg[ii].v = *(const s16x8*)&vg[(size_t)row * M_ + (st + 1) * 64 + sseg];
            }
        }
        const short* Kp = &smem[p * 4352];
        const short* Vp = &smem[8704 + p * 4352];

        s16x4 kf[4][2];
        #pragma unroll
        for (int c = 0; c < 4; c++){
            const short* a = &Kp[(kq * 32 + l32) * 68 + c * 16 + hi * 8];
            kf[c][0] = *(const s16x4*)a; kf[c][1] = *(const s16x4*)(a + 4);
        }
        #pragma unroll
        for (int qt = 0; qt < 2; qt++){
            f32x16 sv = {};
            #pragma unroll
            for (int c = 0; c < 4; c++){
                s16x8 ka = __builtin_shufflevector(kf[c][0], kf[c][1], 0,1,2,3,4,5,6,7);
                sv = MFMA32(ka, qf[qt][c], sv);
            }
            float ls = 0.f;
            unsigned pb[8];
            #pragma unroll
            for (int g = 0; g < 4; g++){
                float p0 = __builtin_amdgcn_exp2f(sv[4*g+0]);
                float p1 = __builtin_amdgcn_exp2f(sv[4*g+1]);
                float p2 = __builtin_amdgcn_exp2f(sv[4*g+2]);
                float p3 = __builtin_amdgcn_exp2f(sv[4*g+3]);
                ls += (p0 + p1) + (p2 + p3);
                pb[2*g]   = __builtin_amdgcn_perm(fbits(p1), fbits(p0), 0x07060302);
                pb[2*g+1] = __builtin_amdgcn_perm(fbits(p3), fbits(p2), 0x07060302);
            }
            lacc[qt] += ls;
            #pragma unroll
            for (int g = 0; g < 4; g++){
                short* d = &Pw[(qt * 32 + l32) * 36 + 8 * g + 4 * hi];
                uint2 u; u.x = pb[2*g]; u.y = pb[2*g+1];
                *(uint2*)d = u;
            }
        }
        asm volatile("s_waitcnt lgkmcnt(0)" ::: "memory");

        // PV: O[q][d] += P(64x32) . V(32x64)
        s16x8 pf[2][2], vf[2][2];
        #pragma unroll
        for (int qt = 0; qt < 2; qt++)
            #pragma unroll
            for (int c = 0; c < 2; c++){
                const short* a = &Pw[(qt * 32 + l32) * 36 + c * 16 + hi * 8];
                pf[qt][c] = __builtin_shufflevector(*(const s16x4*)a, *(const s16x4*)(a + 4),
                                                    0,1,2,3,4,5,6,7);
            }
        #pragma unroll
        for (int dt = 0; dt < 2; dt++)
            #pragma unroll
            for (int c = 0; c < 2; c++){
                const short* a = &Vp[(dt * 32 + l32) * 68 + kq * 32 + c * 16 + hi * 8];
                vf[dt][c] = __builtin_shufflevector(*(const s16x4*)a, *(const s16x4*)(a + 4),
                                                    0,1,2,3,4,5,6,7);
            }
        #pragma unroll
        for (int qt = 0; qt < 2; qt++)
            #pragma unroll
            for (int dt = 0; dt < 2; dt++)
                #pragma unroll
                for (int c = 0; c < 2; c++)
                    oacc[qt][dt] = MFMA32(pf[qt][c], vf[dt][c], oacc[qt][dt]);

        __syncthreads();
        if (st < 31){
            int pn = p ^ 1;
            #pragma unroll
            for (int ii = 0; ii < 2; ii++){
                int row = srow0 + 32 * ii;
                short* kd = &smem[pn * 4352 + row * 68 + sseg];
                *(uint2*)kd = kreg[ii].u[0]; *(uint2*)(kd + 4) = kreg[ii].u[1];
                short* vd = &smem[8704 + pn * 4352 + row * 68 + sseg];
                *(uint2*)vd = vreg[ii].u[0]; *(uint2*)(vd + 4) = vreg[ii].u[1];
            }
        }
    }

    __syncthreads();   // everyone done with K/V/P buffers

    float* LO   = (float*)smem;            // [128][65] f32 (overlays K/V bufs)
    float* Lsum = (float*)&smem[26624];    // 128 f32
    float* Linv = Lsum + 128;              // 128 f32

    float l0[2];
    #pragma unroll
    for (int qt = 0; qt < 2; qt++)
        l0[qt] = lacc[qt] + __shfl_xor(lacc[qt], 32);

    if (kq == 1){
        #pragma unroll
        for (int qt = 0; qt < 2; qt++)
            Lsum[wq * 64 + qt * 32 + l32] = l0[qt];
        #pragma unroll
        for (int qt = 0; qt < 2; qt++)
            #pragma unroll
            for (int dt = 0; dt < 2; dt++)
                #pragma unroll
                for (int e = 0; e < 16; e++){
                    int qrow = wq * 64 + qt * 32 + (e & 3) + 8 * (e >> 2) + 4 * hi;
                    LO[qrow * 65 + dt * 32 + l32] = oacc[qt][dt][e];
                }
    }
    __syncthreads();
    if (kq == 0){
        #pragma unroll
        for (int qt = 0; qt < 2; qt++){
            float lt = l0[qt] + Lsum[wq * 64 + qt * 32 + l32];
            Linv[wq * 64 + qt * 32 + l32] = 1.0f / lt;
        }
        asm volatile("s_waitcnt lgkmcnt(0)" ::: "memory");
        #pragma unroll
        for (int qt = 0; qt < 2; qt++)
            #pragma unroll
            for (int dt = 0; dt < 2; dt++)
                #pragma unroll
                for (int e = 0; e < 16; e++){
                    int qrow = wq * 64 + qt * 32 + (e & 3) + 8 * (e >> 2) + 4 * hi;
                    float val = (oacc[qt][dt][e] + LO[qrow * 65 + dt * 32 + l32]) * Linv[qrow];
                    o[((size_t)(b * N_ + n0 + qrow)) * C_ + h * D_ + dt * 32 + l32] = f2b(val);
                }
    }
}

extern "C" void kernel_launch(void* const* d_in, const int* in_sizes, int n_in,
                              void* d_out, int out_size, void* d_ws, size_t ws_size,
                              hipStream_t stream) {
    const float* query = (const float*)d_in[0];
    const float* key   = (const float*)d_in[1];
    const int*   qpos  = (const int*)d_in[2];
    const int*   kpos  = (const int*)d_in[3];
    const float* Wq    = (const float*)d_in[4];
    const float* bq    = (const float*)d_in[5];
    const float* Wk    = (const float*)d_in[6];
    const float* Wv    = (const float*)d_in[7];
    const float* bv    = (const float*)d_in[8];
    const float* Wo    = (const float*)d_in[9];
    const float* bo    = (const float*)d_in[10];
    float* out = (float*)d_out;

    const size_t E4M = (size_t)4 * 1024 * 1024;
    const size_t E1M = (size_t)1024 * 1024;
    short* ws    = (short*)d_ws;
    short* qbf   = ws;                    // 4M (dead after proj -> reused as attn)
    short* kbf   = qbf   + E4M;           // 4M
    short* wqkvb = kbf   + E4M;           // 3M = [Wq;Wk;Wv]
    short* wob   = wqkvb + 3 * E1M;       // 1M
    short* qproj = wob   + E1M;           // 4M
    short* kproj = qproj + E4M;           // 4M
    short* vT    = kproj + E4M;           // 4M  -> total 24M shorts = 48 MB
    short* attn  = qbf;                   // alias

    // 1) fused converts (12M elements, contiguous dst)
    cvt_all<<<6144, 256, 0, stream>>>(query, key, Wq, Wk, Wv, Wo, ws);

    // 2) fused QKV projection; V stored transposed in epilogue
    gemm_qkv<<<dim3(24, 32), 256, 0, stream>>>(qbf, kbf, wqkvb, bq, bv,
                                               qproj, kproj, vT);

    // 3) RoPE on k only (q-RoPE fused into flash prologue)
    rope_k<<<(B_ * M_ * H_ * 32) / 256, 256, 0, stream>>>(kproj, kpos);

    // 4) flash attention -> attn [B,N,C] bf16
    flash_attn<<<dim3(16, 32), 256, 0, stream>>>(qproj, kproj, vT, attn, qpos);

    // 5) output projection + bias + residual -> f32 out
    gemm_out<<<dim3(16, 32), 256, 0, stream>>>(attn, wob, bo, query, out);
}